// Round 3
// baseline (334.721 us; speedup 1.0000x reference)
//
#include <hip/hip_runtime.h>
#include <hip/hip_bf16.h>
#include <math.h>

// Model: S=8192, D_IN=128, D=2, H=2 (dh=1), FF=3. Inputs f32, output f32
// (verified round 1/2: bf16 input read -> NaN => inputs are f32; bf16 output
// write left upper half of f32-read d_out zeroed => output is f32).
// dh==1 => attention scores are products of scalars: o_i = E[v*exp(q_i k)]/E[exp(q_i k)].
// Taylor: sum_j exp(q k_j) v_j = sum_n q^n/n! * sum_j k_j^n v_j -> 21 moments/head.

#define S_ROWS 8192
#define NT 21               // Taylor terms n=0..20
#define HEAD_STRIDE (2*NT)  // [Z 21][M 21]
#define ATT_STRIDE (2*HEAD_STRIDE)
#define MOM_FLOATS (4*ATT_STRIDE)  // 4 attentions = 336 floats
#define A_ENC1 0
#define A_ENC2 1
#define A_DSA  2
#define A_DCA  3
#define H_OFF  512
#define S1_OFF (H_OFF + 2*S_ROWS)
#define T1_OFF (S1_OFF + 2*S_ROWS)
#define LN_EPS 1e-5f

struct Params {
    const float *x, *mask, *inn_w, *inn_b;
    const float *enc_qkv_w, *enc_qkv_b, *enc_out_w, *enc_out_b;
    const float *enc_ln1_s, *enc_ln1_b, *enc_ln2_s, *enc_ln2_b;
    const float *enc_ff1_w, *enc_ff1_b, *enc_ff2_w, *enc_ff2_b;
    const float *enc_norm_s, *enc_norm_b;
    const float *dsa_qkv_w, *dsa_qkv_b, *dsa_out_w, *dsa_out_b;
    const float *dca_qkv_w, *dca_qkv_b, *dca_out_w, *dca_out_b;
    const float *dec_ln1_s, *dec_ln1_b, *dec_ln2_s, *dec_ln2_b, *dec_ln3_s, *dec_ln3_b;
    const float *dec_ff1_w, *dec_ff1_b, *dec_ff2_w, *dec_ff2_b;
    const float *dec_norm_s, *dec_norm_b, *out_w, *out_b;
    float* ws;
    float* out;
};

__constant__ float INVFACT[NT] = {
    1.0f, 1.0f, 0.5f, 1.6666667e-1f, 4.1666668e-2f, 8.3333338e-3f,
    1.3888889e-3f, 1.9841270e-4f, 2.4801588e-5f, 2.7557319e-6f,
    2.7557319e-7f, 2.5052108e-8f, 2.0876757e-9f, 1.6059044e-10f,
    1.1470746e-11f, 7.6471637e-13f, 4.7794773e-14f, 2.8114573e-15f,
    1.5619207e-16f, 8.2206352e-18f, 4.1103176e-19f
};

__device__ __forceinline__ float wredsum(float x) {
    #pragma unroll
    for (int o = 32; o; o >>= 1) x += __shfl_xor(x, o, 64);
    return x;
}

// accumulate per-head key/value power moments into global ws (wave-reduce + lane0 atomics)
__device__ __forceinline__ void accum_head(float* base, float k, float v, int lane) {
    float pw = 1.0f;
    #pragma unroll
    for (int n = 0; n < NT; ++n) {
        float rz = wredsum(pw);
        float rm = wredsum(pw * v);
        if (lane == 0) {
            atomicAdd(base + n, rz);
            atomicAdd(base + NT + n, rm);
        }
        pw *= k;
    }
}

// Horner-evaluate sum_n q^n/n! Z_n and M_n; return M-series / Z-series
__device__ __forceinline__ float attn_eval(const float* base, float q) {
    const float* Z = base;
    const float* M = base + NT;
    float sz = Z[NT-1] * INVFACT[NT-1];
    float sm = M[NT-1] * INVFACT[NT-1];
    #pragma unroll
    for (int n = NT-2; n >= 0; --n) {
        sz = fmaf(sz, q, Z[n] * INVFACT[n]);
        sm = fmaf(sm, q, M[n] * INVFACT[n]);
    }
    return sm / sz;
}

// LayerNorm over D=2: y0 = d/sqrt(d^2+eps)*s0+b0, y1 = -d/sqrt(d^2+eps)*s1+b1, d=(a0-a1)/2
__device__ __forceinline__ void ln2(float a0, float a1, const float* s, const float* b,
                                    float& y0, float& y1) {
    float d = 0.5f * (a0 - a1);
    float r = d * rsqrtf(fmaf(d, d, LN_EPS));
    y0 = fmaf(r, s[0], b[0]);
    y1 = fmaf(-r, s[1], b[1]);
}

// FFN 2->3(relu)->2, torch Linear layout: w1[f][d] (3x2), w2[d][f] (2x3)
__device__ __forceinline__ void ffn2(float x0, float x1, const float* w1, const float* b1,
                                     const float* w2, const float* b2, float& y0, float& y1) {
    float t0 = fmaxf(fmaf(x0, w1[0], fmaf(x1, w1[1], b1[0])), 0.0f);
    float t1 = fmaxf(fmaf(x0, w1[2], fmaf(x1, w1[3], b1[1])), 0.0f);
    float t2 = fmaxf(fmaf(x0, w1[4], fmaf(x1, w1[5], b1[2])), 0.0f);
    y0 = fmaf(t0, w2[0], fmaf(t1, w2[1], fmaf(t2, w2[2], b2[0])));
    y1 = fmaf(t0, w2[3], fmaf(t1, w2[4], fmaf(t2, w2[5], b2[1])));
}

// K1: h = relu((x*mask) @ inn_w.T + inn_b), one wave per row; block 0 zeroes moments
__global__ __launch_bounds__(256) void k_h(Params p) {
    int tid = threadIdx.x;
    if (blockIdx.x == 0) {
        for (int i = tid; i < MOM_FLOATS; i += 256) p.ws[i] = 0.0f;
    }
    int row  = (blockIdx.x * 256 + tid) >> 6;
    int lane = tid & 63;
    const float2* xr = (const float2*)(p.x    + (size_t)row * 128);
    const float2* mr = (const float2*)(p.mask + (size_t)row * 128);
    const float2* w0 = (const float2*)(p.inn_w);
    const float2* w1 = (const float2*)(p.inn_w + 128);
    float2 xv = xr[lane], mv = mr[lane], wa = w0[lane], wb = w1[lane];
    float xm0 = xv.x * mv.x, xm1 = xv.y * mv.y;
    float a0 = fmaf(xm0, wa.x, xm1 * wa.y);
    float a1 = fmaf(xm0, wb.x, xm1 * wb.y);
    a0 = wredsum(a0);
    a1 = wredsum(a1);
    if (lane == 0) {
        p.ws[H_OFF + 2*row]     = fmaxf(a0 + p.inn_b[0], 0.0f);
        p.ws[H_OFF + 2*row + 1] = fmaxf(a1 + p.inn_b[1], 0.0f);
    }
}

// K2: moments for enc-layer-1 and dec-self-attn (both k,v from h)
__global__ __launch_bounds__(64) void k_p1(Params p) {
    int r = blockIdx.x * 64 + threadIdx.x;
    int lane = threadIdx.x & 63;
    float h0 = p.ws[H_OFF + 2*r], h1 = p.ws[H_OFF + 2*r + 1];
    #pragma unroll
    for (int hh = 0; hh < 2; ++hh) {
        float k = fmaf(h0, p.enc_qkv_w[4 + 2*hh], fmaf(h1, p.enc_qkv_w[5 + 2*hh], p.enc_qkv_b[2 + hh]));
        float v = fmaf(h0, p.enc_qkv_w[8 + 2*hh], fmaf(h1, p.enc_qkv_w[9 + 2*hh], p.enc_qkv_b[4 + hh]));
        accum_head(p.ws + A_ENC1*ATT_STRIDE + hh*HEAD_STRIDE, k, v, lane);
        float kd = fmaf(h0, p.dsa_qkv_w[4 + 2*hh], fmaf(h1, p.dsa_qkv_w[5 + 2*hh], p.dsa_qkv_b[2 + hh]));
        float vd = fmaf(h0, p.dsa_qkv_w[8 + 2*hh], fmaf(h1, p.dsa_qkv_w[9 + 2*hh], p.dsa_qkv_b[4 + hh]));
        accum_head(p.ws + A_DSA*ATT_STRIDE + hh*HEAD_STRIDE, kd, vd, lane);
    }
}

// K3: enc layer 1 (attn -> LN1 -> FFN -> LN2) -> s1; enc layer 2 k,v moments
__global__ __launch_bounds__(64) void k_p2(Params p) {
    int r = blockIdx.x * 64 + threadIdx.x;
    int lane = threadIdx.x & 63;
    float h0 = p.ws[H_OFF + 2*r], h1 = p.ws[H_OFF + 2*r + 1];
    float q0 = fmaf(h0, p.enc_qkv_w[0], fmaf(h1, p.enc_qkv_w[1], p.enc_qkv_b[0]));
    float q1 = fmaf(h0, p.enc_qkv_w[2], fmaf(h1, p.enc_qkv_w[3], p.enc_qkv_b[1]));
    float o0 = attn_eval(p.ws + A_ENC1*ATT_STRIDE,               q0);
    float o1 = attn_eval(p.ws + A_ENC1*ATT_STRIDE + HEAD_STRIDE, q1);
    float m0 = fmaf(o0, p.enc_out_w[0], fmaf(o1, p.enc_out_w[1], p.enc_out_b[0]));
    float m1 = fmaf(o0, p.enc_out_w[2], fmaf(o1, p.enc_out_w[3], p.enc_out_b[1]));
    float u0, u1; ln2(h0 + m0, h1 + m1, p.enc_ln1_s, p.enc_ln1_b, u0, u1);
    float f0, f1; ffn2(u0, u1, p.enc_ff1_w, p.enc_ff1_b, p.enc_ff2_w, p.enc_ff2_b, f0, f1);
    float s0, s1; ln2(u0 + f0, u1 + f1, p.enc_ln2_s, p.enc_ln2_b, s0, s1);
    p.ws[S1_OFF + 2*r] = s0;
    p.ws[S1_OFF + 2*r + 1] = s1;
    const float* W = p.enc_qkv_w + 12;
    const float* B = p.enc_qkv_b + 6;
    #pragma unroll
    for (int hh = 0; hh < 2; ++hh) {
        float k = fmaf(s0, W[4 + 2*hh], fmaf(s1, W[5 + 2*hh], B[2 + hh]));
        float v = fmaf(s0, W[8 + 2*hh], fmaf(s1, W[9 + 2*hh], B[4 + hh]));
        accum_head(p.ws + A_ENC2*ATT_STRIDE + hh*HEAD_STRIDE, k, v, lane);
    }
}

// K4: enc layer 2 -> mem (in-register); dec self-attn -> t1; cross-attn k,v moments from mem
__global__ __launch_bounds__(64) void k_p3(Params p) {
    int r = blockIdx.x * 64 + threadIdx.x;
    int lane = threadIdx.x & 63;
    float s0 = p.ws[S1_OFF + 2*r], s1 = p.ws[S1_OFF + 2*r + 1];
    // ---- encoder layer 2 (layer-1 weight offsets) ----
    const float* W = p.enc_qkv_w + 12;
    const float* B = p.enc_qkv_b + 6;
    float q0 = fmaf(s0, W[0], fmaf(s1, W[1], B[0]));
    float q1 = fmaf(s0, W[2], fmaf(s1, W[3], B[1]));
    float o0 = attn_eval(p.ws + A_ENC2*ATT_STRIDE,               q0);
    float o1 = attn_eval(p.ws + A_ENC2*ATT_STRIDE + HEAD_STRIDE, q1);
    const float* Wo = p.enc_out_w + 4;
    const float* Bo = p.enc_out_b + 2;
    float m0 = fmaf(o0, Wo[0], fmaf(o1, Wo[1], Bo[0]));
    float m1 = fmaf(o0, Wo[2], fmaf(o1, Wo[3], Bo[1]));
    float u0, u1; ln2(s0 + m0, s1 + m1, p.enc_ln1_s + 2, p.enc_ln1_b + 2, u0, u1);
    float f0, f1; ffn2(u0, u1, p.enc_ff1_w + 6, p.enc_ff1_b + 3, p.enc_ff2_w + 6, p.enc_ff2_b + 2, f0, f1);
    float e0, e1; ln2(u0 + f0, u1 + f1, p.enc_ln2_s + 2, p.enc_ln2_b + 2, e0, e1);
    float mem0, mem1; ln2(e0, e1, p.enc_norm_s, p.enc_norm_b, mem0, mem1);
    // ---- decoder self-attn (q from h) -> t1 ----
    float h0 = p.ws[H_OFF + 2*r], h1 = p.ws[H_OFF + 2*r + 1];
    float dq0 = fmaf(h0, p.dsa_qkv_w[0], fmaf(h1, p.dsa_qkv_w[1], p.dsa_qkv_b[0]));
    float dq1 = fmaf(h0, p.dsa_qkv_w[2], fmaf(h1, p.dsa_qkv_w[3], p.dsa_qkv_b[1]));
    float d0 = attn_eval(p.ws + A_DSA*ATT_STRIDE,               dq0);
    float d1 = attn_eval(p.ws + A_DSA*ATT_STRIDE + HEAD_STRIDE, dq1);
    float sm0 = fmaf(d0, p.dsa_out_w[0], fmaf(d1, p.dsa_out_w[1], p.dsa_out_b[0]));
    float sm1 = fmaf(d0, p.dsa_out_w[2], fmaf(d1, p.dsa_out_w[3], p.dsa_out_b[1]));
    float t0, t1; ln2(h0 + sm0, h1 + sm1, p.dec_ln1_s, p.dec_ln1_b, t0, t1);
    p.ws[T1_OFF + 2*r] = t0;
    p.ws[T1_OFF + 2*r + 1] = t1;
    // ---- cross-attn k,v moments from mem ----
    #pragma unroll
    for (int hh = 0; hh < 2; ++hh) {
        float k = fmaf(mem0, p.dca_qkv_w[4 + 2*hh], fmaf(mem1, p.dca_qkv_w[5 + 2*hh], p.dca_qkv_b[2 + hh]));
        float v = fmaf(mem0, p.dca_qkv_w[8 + 2*hh], fmaf(mem1, p.dca_qkv_w[9 + 2*hh], p.dca_qkv_b[4 + hh]));
        accum_head(p.ws + A_DCA*ATT_STRIDE + hh*HEAD_STRIDE, k, v, lane);
    }
}

// K5: cross-attn -> LN2 -> FFN -> LN3 -> final LN -> tanh(out proj) -> d_out (f32)
__global__ __launch_bounds__(64) void k_p4(Params p) {
    int r = blockIdx.x * 64 + threadIdx.x;
    float t0 = p.ws[T1_OFF + 2*r], t1 = p.ws[T1_OFF + 2*r + 1];
    float q0 = fmaf(t0, p.dca_qkv_w[0], fmaf(t1, p.dca_qkv_w[1], p.dca_qkv_b[0]));
    float q1 = fmaf(t0, p.dca_qkv_w[2], fmaf(t1, p.dca_qkv_w[3], p.dca_qkv_b[1]));
    float c0 = attn_eval(p.ws + A_DCA*ATT_STRIDE,               q0);
    float c1 = attn_eval(p.ws + A_DCA*ATT_STRIDE + HEAD_STRIDE, q1);
    float m0 = fmaf(c0, p.dca_out_w[0], fmaf(c1, p.dca_out_w[1], p.dca_out_b[0]));
    float m1 = fmaf(c0, p.dca_out_w[2], fmaf(c1, p.dca_out_w[3], p.dca_out_b[1]));
    float u0, u1; ln2(t0 + m0, t1 + m1, p.dec_ln2_s, p.dec_ln2_b, u0, u1);
    float f0, f1; ffn2(u0, u1, p.dec_ff1_w, p.dec_ff1_b, p.dec_ff2_w, p.dec_ff2_b, f0, f1);
    float w0, w1; ln2(u0 + f0, u1 + f1, p.dec_ln3_s, p.dec_ln3_b, w0, w1);
    float z0, z1; ln2(w0, w1, p.dec_norm_s, p.dec_norm_b, z0, z1);
    float y = tanhf(fmaf(z0, p.out_w[0], fmaf(z1, p.out_w[1], p.out_b[0])));
    p.out[r] = y;
}

extern "C" void kernel_launch(void* const* d_in, const int* in_sizes, int n_in,
                              void* d_out, int out_size, void* d_ws, size_t ws_size,
                              hipStream_t stream) {
    Params p;
    p.x          = (const float*)d_in[0];
    p.mask       = (const float*)d_in[1];
    p.inn_w      = (const float*)d_in[2];
    p.inn_b      = (const float*)d_in[3];
    p.enc_qkv_w  = (const float*)d_in[4];
    p.enc_qkv_b  = (const float*)d_in[5];
    p.enc_out_w  = (const float*)d_in[6];
    p.enc_out_b  = (const float*)d_in[7];
    p.enc_ln1_s  = (const float*)d_in[8];
    p.enc_ln1_b  = (const float*)d_in[9];
    p.enc_ln2_s  = (const float*)d_in[10];
    p.enc_ln2_b  = (const float*)d_in[11];
    p.enc_ff1_w  = (const float*)d_in[12];
    p.enc_ff1_b  = (const float*)d_in[13];
    p.enc_ff2_w  = (const float*)d_in[14];
    p.enc_ff2_b  = (const float*)d_in[15];
    p.enc_norm_s = (const float*)d_in[16];
    p.enc_norm_b = (const float*)d_in[17];
    p.dsa_qkv_w  = (const float*)d_in[18];
    p.dsa_qkv_b  = (const float*)d_in[19];
    p.dsa_out_w  = (const float*)d_in[20];
    p.dsa_out_b  = (const float*)d_in[21];
    p.dca_qkv_w  = (const float*)d_in[22];
    p.dca_qkv_b  = (const float*)d_in[23];
    p.dca_out_w  = (const float*)d_in[24];
    p.dca_out_b  = (const float*)d_in[25];
    p.dec_ln1_s  = (const float*)d_in[26];
    p.dec_ln1_b  = (const float*)d_in[27];
    p.dec_ln2_s  = (const float*)d_in[28];
    p.dec_ln2_b  = (const float*)d_in[29];
    p.dec_ln3_s  = (const float*)d_in[30];
    p.dec_ln3_b  = (const float*)d_in[31];
    p.dec_ff1_w  = (const float*)d_in[32];
    p.dec_ff1_b  = (const float*)d_in[33];
    p.dec_ff2_w  = (const float*)d_in[34];
    p.dec_ff2_b  = (const float*)d_in[35];
    p.dec_norm_s = (const float*)d_in[36];
    p.dec_norm_b = (const float*)d_in[37];
    p.out_w      = (const float*)d_in[38];
    p.out_b      = (const float*)d_in[39];
    p.ws  = (float*)d_ws;
    p.out = (float*)d_out;

    hipLaunchKernelGGL(k_h,  dim3(2048), dim3(256), 0, stream, p);  // h + zero moments
    hipLaunchKernelGGL(k_p1, dim3(128),  dim3(64),  0, stream, p);  // enc1 + dec-self moments
    hipLaunchKernelGGL(k_p2, dim3(128),  dim3(64),  0, stream, p);  // enc1 layer -> s1; enc2 moments
    hipLaunchKernelGGL(k_p3, dim3(128),  dim3(64),  0, stream, p);  // enc2 -> mem; self-attn -> t1; cross moments
    hipLaunchKernelGGL(k_p4, dim3(128),  dim3(64),  0, stream, p);  // cross-attn -> output
}

// Round 4
// 199.167 us; speedup vs baseline: 1.6806x; 1.6806x over previous
//
#include <hip/hip_runtime.h>
#include <hip/hip_bf16.h>
#include <math.h>

// Model: S=8192, D_IN=128, D=2, H=2 (dh=1), FF=3. Inputs f32, output f32.
// dh==1 => attention is scalar-score: o_i = E[v*exp(q_i k)]/E[exp(q_i k)].
// Taylor: sum_j exp(q k_j) v_j = sum_n q^n/n! * sum_j k_j^n v_j -> 21 moments/head.
// R4 restructure: moment accumulation = per-lane register arrays over rows,
// ONE pipelined butterfly per series (independent shfls), <=32 same-address atomics.

#define S_ROWS 8192
#define NT 21               // Taylor terms n=0..20
#define HEAD_STRIDE (2*NT)  // [Z 21][M 21]
#define ATT_STRIDE (2*HEAD_STRIDE)
#define MOM_FLOATS (4*ATT_STRIDE)  // 336 floats
#define A_ENC1 0
#define A_ENC2 1
#define A_DSA  2
#define A_DCA  3
#define H_OFF  512
#define S1_OFF (H_OFF + 2*S_ROWS)
#define T1_OFF (S1_OFF + 2*S_ROWS)
#define LN_EPS 1e-5f

struct Params {
    const float *x, *mask, *inn_w, *inn_b;
    const float *enc_qkv_w, *enc_qkv_b, *enc_out_w, *enc_out_b;
    const float *enc_ln1_s, *enc_ln1_b, *enc_ln2_s, *enc_ln2_b;
    const float *enc_ff1_w, *enc_ff1_b, *enc_ff2_w, *enc_ff2_b;
    const float *enc_norm_s, *enc_norm_b;
    const float *dsa_qkv_w, *dsa_qkv_b, *dsa_out_w, *dsa_out_b;
    const float *dca_qkv_w, *dca_qkv_b, *dca_out_w, *dca_out_b;
    const float *dec_ln1_s, *dec_ln1_b, *dec_ln2_s, *dec_ln2_b, *dec_ln3_s, *dec_ln3_b;
    const float *dec_ff1_w, *dec_ff1_b, *dec_ff2_w, *dec_ff2_b;
    const float *dec_norm_s, *dec_norm_b, *out_w, *out_b;
    float* ws;
    float* out;
};

__constant__ float INVFACT[NT] = {
    1.0f, 1.0f, 0.5f, 1.6666667e-1f, 4.1666668e-2f, 8.3333338e-3f,
    1.3888889e-3f, 1.9841270e-4f, 2.4801588e-5f, 2.7557319e-6f,
    2.7557319e-7f, 2.5052108e-8f, 2.0876757e-9f, 1.6059044e-10f,
    1.1470746e-11f, 7.6471637e-13f, 4.7794773e-14f, 2.8114573e-15f,
    1.5619207e-16f, 8.2206352e-18f, 4.1103176e-19f
};

__device__ __forceinline__ float wredsum(float x) {
    #pragma unroll
    for (int o = 32; o; o >>= 1) x += __shfl_xor(x, o, 64);
    return x;
}

// butterfly-reduce an N-float register array across the wave; shfls within a
// stage are independent -> pipeline (vs 6-deep dependent chain per value).
template<int N>
__device__ __forceinline__ void wred_arr(float* a) {
    #pragma unroll
    for (int o = 32; o; o >>= 1) {
        #pragma unroll
        for (int n = 0; n < N; ++n) a[n] += __shfl_xor(a[n], o, 64);
    }
}

// Horner-evaluate sum_n q^n/n! Z_n and M_n; return M-series / Z-series
__device__ __forceinline__ float attn_eval(const float* base, float q) {
    const float* Z = base;
    const float* M = base + NT;
    float sz = Z[NT-1] * INVFACT[NT-1];
    float sm = M[NT-1] * INVFACT[NT-1];
    #pragma unroll
    for (int n = NT-2; n >= 0; --n) {
        sz = fmaf(sz, q, Z[n] * INVFACT[n]);
        sm = fmaf(sm, q, M[n] * INVFACT[n]);
    }
    return sm / sz;
}

__device__ __forceinline__ void ln2(float a0, float a1, const float* s, const float* b,
                                    float& y0, float& y1) {
    float d = 0.5f * (a0 - a1);
    float r = d * rsqrtf(fmaf(d, d, LN_EPS));
    y0 = fmaf(r, s[0], b[0]);
    y1 = fmaf(-r, s[1], b[1]);
}

__device__ __forceinline__ void ffn2(float x0, float x1, const float* w1, const float* b1,
                                     const float* w2, const float* b2, float& y0, float& y1) {
    float t0 = fmaxf(fmaf(x0, w1[0], fmaf(x1, w1[1], b1[0])), 0.0f);
    float t1 = fmaxf(fmaf(x0, w1[2], fmaf(x1, w1[3], b1[1])), 0.0f);
    float t2 = fmaxf(fmaf(x0, w1[4], fmaf(x1, w1[5], b1[2])), 0.0f);
    y0 = fmaf(t0, w2[0], fmaf(t1, w2[1], fmaf(t2, w2[2], b2[0])));
    y1 = fmaf(t0, w2[3], fmaf(t1, w2[4], fmaf(t2, w2[5], b2[1])));
}

// local moment accumulation for one row (k,v) into z[NT], m[NT]
__device__ __forceinline__ void accum_local(float* z, float* m, float k, float v) {
    float pw = 1.0f;
    #pragma unroll
    for (int n = 0; n < NT; ++n) { z[n] += pw; m[n] += pw * v; pw *= k; }
}

__device__ __forceinline__ void flush_atomic(float* base, const float* z, const float* m, int lane) {
    if (lane == 0) {
        #pragma unroll
        for (int n = 0; n < NT; ++n) {
            atomicAdd(base + n,      z[n]);
            atomicAdd(base + NT + n, m[n]);
        }
    }
}

// K1: h = relu((x*mask) @ inn_w.T + inn_b), one wave per row; block 0 zeroes moments
__global__ __launch_bounds__(256) void k_h(Params p) {
    int tid = threadIdx.x;
    if (blockIdx.x == 0) {
        for (int i = tid; i < MOM_FLOATS; i += 256) p.ws[i] = 0.0f;
    }
    int row  = (blockIdx.x * 256 + tid) >> 6;
    int lane = tid & 63;
    const float2* xr = (const float2*)(p.x    + (size_t)row * 128);
    const float2* mr = (const float2*)(p.mask + (size_t)row * 128);
    const float2* w0 = (const float2*)(p.inn_w);
    const float2* w1 = (const float2*)(p.inn_w + 128);
    float2 xv = xr[lane], mv = mr[lane], wa = w0[lane], wb = w1[lane];
    float xm0 = xv.x * mv.x, xm1 = xv.y * mv.y;
    float a0 = fmaf(xm0, wa.x, xm1 * wa.y);
    float a1 = fmaf(xm0, wb.x, xm1 * wb.y);
    a0 = wredsum(a0);
    a1 = wredsum(a1);
    if (lane == 0) {
        p.ws[H_OFF + 2*row]     = fmaxf(a0 + p.inn_b[0], 0.0f);
        p.ws[H_OFF + 2*row + 1] = fmaxf(a1 + p.inn_b[1], 0.0f);
    }
}

// K2: moments for enc1 + dsa (4 series). 16 blocks x 256; wave w owns series w,
// covering the block's 512 rows (8 rows/lane, register-local), one butterfly.
__global__ __launch_bounds__(256) void k_p1(Params p) {
    int wave = threadIdx.x >> 6, lane = threadIdx.x & 63;
    int row0 = blockIdx.x * 512;
    const float* W = (wave < 2) ? p.enc_qkv_w : p.dsa_qkv_w;
    const float* B = (wave < 2) ? p.enc_qkv_b : p.dsa_qkv_b;
    int hh = wave & 1;
    float kw0 = W[4+2*hh], kw1 = W[5+2*hh], kb = B[2+hh];
    float vw0 = W[8+2*hh], vw1 = W[9+2*hh], vb = B[4+hh];
    float z[NT], m[NT];
    #pragma unroll
    for (int n = 0; n < NT; ++n) { z[n] = 0.0f; m[n] = 0.0f; }
    for (int i = lane; i < 512; i += 64) {
        int r = row0 + i;
        float h0 = p.ws[H_OFF + 2*r], h1 = p.ws[H_OFF + 2*r + 1];
        float k = fmaf(h0, kw0, fmaf(h1, kw1, kb));
        float v = fmaf(h0, vw0, fmaf(h1, vw1, vb));
        accum_local(z, m, k, v);
    }
    wred_arr<NT>(z);
    wred_arr<NT>(m);
    float* base = p.ws + ((wave < 2) ? A_ENC1 : A_DSA)*ATT_STRIDE + hh*HEAD_STRIDE;
    flush_atomic(base, z, m, lane);  // 16 same-address atomics total
}

// K3: enc layer 1 (attn->LN->FFN->LN) -> s1 (global + LDS); then enc2 moments.
// 16 blocks x 256: phase1 2 rows/thread; phase2 wave-pair per series.
__global__ __launch_bounds__(256) void k_p2(Params p) {
    __shared__ float sl[1024];  // 512 rows x 2
    int tid = threadIdx.x;
    int row0 = blockIdx.x * 512;
    #pragma unroll
    for (int rr = 0; rr < 2; ++rr) {
        int i = tid + rr*256;
        int r = row0 + i;
        float h0 = p.ws[H_OFF + 2*r], h1 = p.ws[H_OFF + 2*r + 1];
        float q0 = fmaf(h0, p.enc_qkv_w[0], fmaf(h1, p.enc_qkv_w[1], p.enc_qkv_b[0]));
        float q1 = fmaf(h0, p.enc_qkv_w[2], fmaf(h1, p.enc_qkv_w[3], p.enc_qkv_b[1]));
        float o0 = attn_eval(p.ws + A_ENC1*ATT_STRIDE,               q0);
        float o1 = attn_eval(p.ws + A_ENC1*ATT_STRIDE + HEAD_STRIDE, q1);
        float m0 = fmaf(o0, p.enc_out_w[0], fmaf(o1, p.enc_out_w[1], p.enc_out_b[0]));
        float m1 = fmaf(o0, p.enc_out_w[2], fmaf(o1, p.enc_out_w[3], p.enc_out_b[1]));
        float u0, u1; ln2(h0 + m0, h1 + m1, p.enc_ln1_s, p.enc_ln1_b, u0, u1);
        float f0, f1; ffn2(u0, u1, p.enc_ff1_w, p.enc_ff1_b, p.enc_ff2_w, p.enc_ff2_b, f0, f1);
        float s0, s1; ln2(u0 + f0, u1 + f1, p.enc_ln2_s, p.enc_ln2_b, s0, s1);
        p.ws[S1_OFF + 2*r]     = s0;
        p.ws[S1_OFF + 2*r + 1] = s1;
        sl[2*i]   = s0;
        sl[2*i+1] = s1;
    }
    __syncthreads();
    int wave = tid >> 6, lane = tid & 63;
    int hh = wave & 1, half = wave >> 1;
    const float* W = p.enc_qkv_w + 12;
    const float* B = p.enc_qkv_b + 6;
    float kw0 = W[4+2*hh], kw1 = W[5+2*hh], kb = B[2+hh];
    float vw0 = W[8+2*hh], vw1 = W[9+2*hh], vb = B[4+hh];
    float z[NT], m[NT];
    #pragma unroll
    for (int n = 0; n < NT; ++n) { z[n] = 0.0f; m[n] = 0.0f; }
    #pragma unroll
    for (int j = 0; j < 4; ++j) {
        int i = half*256 + j*64 + lane;
        float s0 = sl[2*i], s1 = sl[2*i+1];
        float k = fmaf(s0, kw0, fmaf(s1, kw1, kb));
        float v = fmaf(s0, vw0, fmaf(s1, vw1, vb));
        accum_local(z, m, k, v);
    }
    wred_arr<NT>(z);
    wred_arr<NT>(m);
    flush_atomic(p.ws + A_ENC2*ATT_STRIDE + hh*HEAD_STRIDE, z, m, lane);  // 32/addr
}

// K4: enc layer 2 -> mem (LDS); dec self-attn -> t1; then cross-attn moments from mem.
__global__ __launch_bounds__(256) void k_p3(Params p) {
    __shared__ float ml[1024];  // mem: 512 rows x 2
    int tid = threadIdx.x;
    int row0 = blockIdx.x * 512;
    const float* W = p.enc_qkv_w + 12;
    const float* B = p.enc_qkv_b + 6;
    const float* Wo = p.enc_out_w + 4;
    const float* Bo = p.enc_out_b + 2;
    #pragma unroll
    for (int rr = 0; rr < 2; ++rr) {
        int i = tid + rr*256;
        int r = row0 + i;
        float s0 = p.ws[S1_OFF + 2*r], s1 = p.ws[S1_OFF + 2*r + 1];
        float q0 = fmaf(s0, W[0], fmaf(s1, W[1], B[0]));
        float q1 = fmaf(s0, W[2], fmaf(s1, W[3], B[1]));
        float o0 = attn_eval(p.ws + A_ENC2*ATT_STRIDE,               q0);
        float o1 = attn_eval(p.ws + A_ENC2*ATT_STRIDE + HEAD_STRIDE, q1);
        float m0 = fmaf(o0, Wo[0], fmaf(o1, Wo[1], Bo[0]));
        float m1 = fmaf(o0, Wo[2], fmaf(o1, Wo[3], Bo[1]));
        float u0, u1; ln2(s0 + m0, s1 + m1, p.enc_ln1_s + 2, p.enc_ln1_b + 2, u0, u1);
        float f0, f1; ffn2(u0, u1, p.enc_ff1_w + 6, p.enc_ff1_b + 3, p.enc_ff2_w + 6, p.enc_ff2_b + 2, f0, f1);
        float e0, e1; ln2(u0 + f0, u1 + f1, p.enc_ln2_s + 2, p.enc_ln2_b + 2, e0, e1);
        float mem0, mem1; ln2(e0, e1, p.enc_norm_s, p.enc_norm_b, mem0, mem1);
        ml[2*i]   = mem0;
        ml[2*i+1] = mem1;
        // decoder self-attn (q from h) -> t1
        float h0 = p.ws[H_OFF + 2*r], h1 = p.ws[H_OFF + 2*r + 1];
        float dq0 = fmaf(h0, p.dsa_qkv_w[0], fmaf(h1, p.dsa_qkv_w[1], p.dsa_qkv_b[0]));
        float dq1 = fmaf(h0, p.dsa_qkv_w[2], fmaf(h1, p.dsa_qkv_w[3], p.dsa_qkv_b[1]));
        float d0 = attn_eval(p.ws + A_DSA*ATT_STRIDE,               dq0);
        float d1 = attn_eval(p.ws + A_DSA*ATT_STRIDE + HEAD_STRIDE, dq1);
        float sm0 = fmaf(d0, p.dsa_out_w[0], fmaf(d1, p.dsa_out_w[1], p.dsa_out_b[0]));
        float sm1 = fmaf(d0, p.dsa_out_w[2], fmaf(d1, p.dsa_out_w[3], p.dsa_out_b[1]));
        float t0, t1; ln2(h0 + sm0, h1 + sm1, p.dec_ln1_s, p.dec_ln1_b, t0, t1);
        p.ws[T1_OFF + 2*r]     = t0;
        p.ws[T1_OFF + 2*r + 1] = t1;
    }
    __syncthreads();
    int wave = tid >> 6, lane = tid & 63;
    int hh = wave & 1, half = wave >> 1;
    float kw0 = p.dca_qkv_w[4+2*hh], kw1 = p.dca_qkv_w[5+2*hh], kb = p.dca_qkv_b[2+hh];
    float vw0 = p.dca_qkv_w[8+2*hh], vw1 = p.dca_qkv_w[9+2*hh], vb = p.dca_qkv_b[4+hh];
    float z[NT], m[NT];
    #pragma unroll
    for (int n = 0; n < NT; ++n) { z[n] = 0.0f; m[n] = 0.0f; }
    #pragma unroll
    for (int j = 0; j < 4; ++j) {
        int i = half*256 + j*64 + lane;
        float mem0 = ml[2*i], mem1 = ml[2*i+1];
        float k = fmaf(mem0, kw0, fmaf(mem1, kw1, kb));
        float v = fmaf(mem0, vw0, fmaf(mem1, vw1, vb));
        accum_local(z, m, k, v);
    }
    wred_arr<NT>(z);
    wred_arr<NT>(m);
    flush_atomic(p.ws + A_DCA*ATT_STRIDE + hh*HEAD_STRIDE, z, m, lane);
}

// K5: cross-attn -> LN2 -> FFN -> LN3 -> final LN -> tanh(out proj) -> d_out (f32)
__global__ __launch_bounds__(256) void k_p4(Params p) {
    int r = blockIdx.x * 256 + threadIdx.x;
    float t0 = p.ws[T1_OFF + 2*r], t1 = p.ws[T1_OFF + 2*r + 1];
    float q0 = fmaf(t0, p.dca_qkv_w[0], fmaf(t1, p.dca_qkv_w[1], p.dca_qkv_b[0]));
    float q1 = fmaf(t0, p.dca_qkv_w[2], fmaf(t1, p.dca_qkv_w[3], p.dca_qkv_b[1]));
    float c0 = attn_eval(p.ws + A_DCA*ATT_STRIDE,               q0);
    float c1 = attn_eval(p.ws + A_DCA*ATT_STRIDE + HEAD_STRIDE, q1);
    float m0 = fmaf(c0, p.dca_out_w[0], fmaf(c1, p.dca_out_w[1], p.dca_out_b[0]));
    float m1 = fmaf(c0, p.dca_out_w[2], fmaf(c1, p.dca_out_w[3], p.dca_out_b[1]));
    float u0, u1; ln2(t0 + m0, t1 + m1, p.dec_ln2_s, p.dec_ln2_b, u0, u1);
    float f0, f1; ffn2(u0, u1, p.dec_ff1_w, p.dec_ff1_b, p.dec_ff2_w, p.dec_ff2_b, f0, f1);
    float w0, w1; ln2(u0 + f0, u1 + f1, p.dec_ln3_s, p.dec_ln3_b, w0, w1);
    float z0, z1; ln2(w0, w1, p.dec_norm_s, p.dec_norm_b, z0, z1);
    float y = tanhf(fmaf(z0, p.out_w[0], fmaf(z1, p.out_w[1], p.out_b[0])));
    p.out[r] = y;
}

extern "C" void kernel_launch(void* const* d_in, const int* in_sizes, int n_in,
                              void* d_out, int out_size, void* d_ws, size_t ws_size,
                              hipStream_t stream) {
    Params p;
    p.x          = (const float*)d_in[0];
    p.mask       = (const float*)d_in[1];
    p.inn_w      = (const float*)d_in[2];
    p.inn_b      = (const float*)d_in[3];
    p.enc_qkv_w  = (const float*)d_in[4];
    p.enc_qkv_b  = (const float*)d_in[5];
    p.enc_out_w  = (const float*)d_in[6];
    p.enc_out_b  = (const float*)d_in[7];
    p.enc_ln1_s  = (const float*)d_in[8];
    p.enc_ln1_b  = (const float*)d_in[9];
    p.enc_ln2_s  = (const float*)d_in[10];
    p.enc_ln2_b  = (const float*)d_in[11];
    p.enc_ff1_w  = (const float*)d_in[12];
    p.enc_ff1_b  = (const float*)d_in[13];
    p.enc_ff2_w  = (const float*)d_in[14];
    p.enc_ff2_b  = (const float*)d_in[15];
    p.enc_norm_s = (const float*)d_in[16];
    p.enc_norm_b = (const float*)d_in[17];
    p.dsa_qkv_w  = (const float*)d_in[18];
    p.dsa_qkv_b  = (const float*)d_in[19];
    p.dsa_out_w  = (const float*)d_in[20];
    p.dsa_out_b  = (const float*)d_in[21];
    p.dca_qkv_w  = (const float*)d_in[22];
    p.dca_qkv_b  = (const float*)d_in[23];
    p.dca_out_w  = (const float*)d_in[24];
    p.dca_out_b  = (const float*)d_in[25];
    p.dec_ln1_s  = (const float*)d_in[26];
    p.dec_ln1_b  = (const float*)d_in[27];
    p.dec_ln2_s  = (const float*)d_in[28];
    p.dec_ln2_b  = (const float*)d_in[29];
    p.dec_ln3_s  = (const float*)d_in[30];
    p.dec_ln3_b  = (const float*)d_in[31];
    p.dec_ff1_w  = (const float*)d_in[32];
    p.dec_ff1_b  = (const float*)d_in[33];
    p.dec_ff2_w  = (const float*)d_in[34];
    p.dec_ff2_b  = (const float*)d_in[35];
    p.dec_norm_s = (const float*)d_in[36];
    p.dec_norm_b = (const float*)d_in[37];
    p.out_w      = (const float*)d_in[38];
    p.out_b      = (const float*)d_in[39];
    p.ws  = (float*)d_ws;
    p.out = (float*)d_out;

    hipLaunchKernelGGL(k_h,  dim3(2048), dim3(256), 0, stream, p);  // h + zero moments
    hipLaunchKernelGGL(k_p1, dim3(16),   dim3(256), 0, stream, p);  // enc1 + dsa moments
    hipLaunchKernelGGL(k_p2, dim3(16),   dim3(256), 0, stream, p);  // enc1 layer -> s1; enc2 moments
    hipLaunchKernelGGL(k_p3, dim3(16),   dim3(256), 0, stream, p);  // enc2 -> mem; dsa -> t1; dca moments
    hipLaunchKernelGGL(k_p4, dim3(32),   dim3(256), 0, stream, p);  // cross-attn -> output
}